// Round 12
// baseline (1910.065 us; speedup 1.0000x reference)
//
#include <hip/hip_runtime.h>
#include <stdint.h>

// Periodic radius-graph (min-image), K nearest within cutoff, self-loop padded.
// N=8192, box 50^3, cutoff 6, K=32.
// Output (f32): [src (N*K) | dst (N*K) | weight (N*K) | vec (N*K,3)]
//
// Structure: no LDS, no atomics, no compaction (machinery-risk-free rescan).
// Selection = 32 rounds; each round rescans all 8192 candidates and takes the
// wave-wide min key strictly greater than the previous round's winner.
// key = ((f32bits(d2)<<13)|j)+1: unique, ascending d2, ties -> lower j.
//
// d2 expression "E" (SIMD hsum shape over [dx2,dy2,dz2,0]):
//   d2 = RN( RN(dx*dx + dz*dz) + dy*dy )  with each square rounded first.

constexpr int NATOMS = 8192;
constexpr int KNB    = 32;
constexpr int NK     = NATOMS * KNB;  // 262144 edges

__global__ __launch_bounds__(256) void radius_graph_rescan(
    const float* __restrict__ pos,        // [N,3] f32
    float* __restrict__ out)
{
#pragma clang fp contract(off)
    const int wv   = threadIdx.x >> 6;
    const int lane = threadIdx.x & 63;
    const int i    = (blockIdx.x << 2) + wv;   // atom handled by this wave

    const float xi = pos[3*i + 0];
    const float yi = pos[3*i + 1];
    const float zi = pos[3*i + 2];

    unsigned long long prev = 0ULL;   // all valid keys are >= 1
    int mydst = i;                    // lane k (k<32) records round-k winner

    for (int k = 0; k < KNB; ++k) {
        unsigned long long best = ~0ULL;
        for (int j = lane; j < NATOMS; j += 64) {
            float dx = xi - pos[3*j + 0];
            float dy = yi - pos[3*j + 1];
            float dz = zi - pos[3*j + 2];
            // min-image wrap; equivalent to d - round(d/50)*50 for any pair
            // that can be in-cutoff (no f32 value divides onto the 0.5
            // round boundary; wrapped subtraction is Sterbenz-exact).
            dx = (dx >  25.0f) ? dx - 50.0f : dx;
            dx = (dx < -25.0f) ? dx + 50.0f : dx;
            dy = (dy >  25.0f) ? dy - 50.0f : dy;
            dy = (dy < -25.0f) ? dy + 50.0f : dy;
            dz = (dz >  25.0f) ? dz - 50.0f : dz;
            dz = (dz < -25.0f) ? dz + 50.0f : dz;
            // expression E: individually rounded squares, (x+z) then +y
            float sx = dx * dx;
            float sy = dy * dy;
            float sz = dz * dz;
            float d2 = sx + sz;
            d2 = d2 + sy;
            if (d2 <= 36.0f) {
                unsigned long long key =
                    ((((unsigned long long)__float_as_uint(d2)) << 13)
                     | (unsigned long long)(unsigned)j) + 1ULL;
                if (key > prev && key < best) best = key;
            }
        }
        // wave-wide min (butterfly over 64 lanes)
        #pragma unroll
        for (int off = 32; off > 0; off >>= 1) {
            unsigned long long o = __shfl_xor(best, off, 64);
            if (o < best) best = o;
        }
        int dst = (best == ~0ULL) ? i : (int)((best - 1ULL) & 0x1fffULL);
        if (lane == k) mydst = dst;
        prev = best;   // uniform across lanes; sentinel sticks (pads forever)
    }

    // ---- emit: lanes 0..31, one edge each (f32 stores) ----
    if (lane < KNB) {
        const int e = i * KNB + lane;
        const int j = mydst;
        // edge_vec uses RAW (unwrapped) positions, per the reference.
        float ex = xi - pos[3*j + 0];
        float ey = yi - pos[3*j + 1];
        float ez = zi - pos[3*j + 2];
        float v2 = ex * ex;
        v2 = v2 + ey * ey;
        v2 = v2 + ez * ez;
        float w = (j != i) ? sqrtf(v2) : 0.0f;

        out[e]                = (float)i;   // src
        out[NK + e]           = (float)j;   // dst
        out[2 * NK + e]       = w;          // weight
        out[3 * NK + 3*e + 0] = ex;         // vec.x
        out[3 * NK + 3*e + 1] = ey;         // vec.y
        out[3 * NK + 3*e + 2] = ez;         // vec.z
    }
}

extern "C" void kernel_launch(void* const* d_in, const int* in_sizes, int n_in,
                              void* d_out, int out_size, void* d_ws, size_t ws_size,
                              hipStream_t stream) {
    const float* pos = (const float*)d_in[0];
    // d_in[1] = batch (all zeros, single system) -> ignored
    float* out = (float*)d_out;
    radius_graph_rescan<<<NATOMS / 4, 256, 0, stream>>>(pos, out);
}

// Round 17
// 143.089 us; speedup vs baseline: 13.3488x; 13.3488x over previous
//
#include <hip/hip_runtime.h>
#include <stdint.h>

// Periodic radius-graph (min-image), K nearest within cutoff, self-loop padded.
// N=8192, box 50^3, cutoff 6, K=32.
// Output (f32): [src (N*K) | dst (N*K) | weight (N*K) | vec (N*K,3)]
//
// PROVEN (r12, absmax 0.0): d2 expression "E" = RN(RN(dx*dx+dz*dz)+dy*dy)
// (XLA:CPU SIMD hsum shape), key=((f32bits(d2)<<13)|j)+1 with prev-successor
// selection (ascending d2, ties -> lower j), branch-based min-image wrap,
// raw-position edge vectors, f32 stores.
//
// THIS ROUND: drop the 32x rescan redundancy. Single pass collects the ~60
// in-cutoff candidates per atom into LDS (CAP=128, overflow p~1e-13), then
// runs the same prev-successor selection over the compacted keys.

constexpr int NATOMS = 8192;
constexpr int KNB    = 32;
constexpr int CAP    = 128;
constexpr int NK     = NATOMS * KNB;  // 262144 edges

__global__ __launch_bounds__(256) void radius_graph_1pass(
    const float* __restrict__ pos,        // [N,3] f32
    float* __restrict__ out)
{
#pragma clang fp contract(off)
    __shared__ unsigned long long s_key[4][CAP];
    __shared__ int s_cnt[4];

    const int wv   = threadIdx.x >> 6;
    const int lane = threadIdx.x & 63;
    const int i    = (blockIdx.x << 2) + wv;   // atom handled by this wave

    const float xi = pos[3*i + 0];
    const float yi = pos[3*i + 1];
    const float zi = pos[3*i + 2];

    if (lane == 0) s_cnt[wv] = 0;
    __syncthreads();   // uniform trip counts across all 4 waves

    // ---- pass 1: single scan, compact candidates (d2 <= 36) into LDS ----
    for (int j = lane; j < NATOMS; j += 64) {
        float dx = xi - pos[3*j + 0];
        float dy = yi - pos[3*j + 1];
        float dz = zi - pos[3*j + 2];
        // min-image wrap; bitwise-equivalent to d - round(d/50)*50 for any
        // pair that can be in-cutoff (proven r12: absmax 0.0).
        dx = (dx >  25.0f) ? dx - 50.0f : dx;
        dx = (dx < -25.0f) ? dx + 50.0f : dx;
        dy = (dy >  25.0f) ? dy - 50.0f : dy;
        dy = (dy < -25.0f) ? dy + 50.0f : dy;
        dz = (dz >  25.0f) ? dz - 50.0f : dz;
        dz = (dz < -25.0f) ? dz + 50.0f : dz;
        // expression E (proven): rounded squares, (x+z) then +y
        float sx = dx * dx;
        float sy = dy * dy;
        float sz = dz * dz;
        float d2 = sx + sz;
        d2 = d2 + sy;
        if (d2 <= 36.0f) {
            unsigned long long key =
                ((((unsigned long long)__float_as_uint(d2)) << 13)
                 | (unsigned long long)(unsigned)j) + 1ULL;
            int slot = atomicAdd(&s_cnt[wv], 1);
            if (slot < CAP) s_key[wv][slot] = key;
        }
    }
    __syncthreads();

    int M = s_cnt[wv];
    if (M > CAP) M = CAP;

    // ---- pass 2: prev-successor selection over compacted keys (r12 logic) ----
    unsigned long long k0 = ~0ULL, k1 = ~0ULL;
    if (lane < M)      k0 = s_key[wv][lane];
    if (lane + 64 < M) k1 = s_key[wv][lane + 64];

    unsigned long long prev = 0ULL;   // all valid keys >= 1
    int mydst = i;                    // lane k (k<32) records round-k winner
    for (int k = 0; k < KNB; ++k) {
        unsigned long long best = ~0ULL;
        if (k0 > prev && k0 < best) best = k0;
        if (k1 > prev && k1 < best) best = k1;
        #pragma unroll
        for (int off = 32; off > 0; off >>= 1) {
            unsigned long long o = __shfl_xor(best, off, 64);
            if (o < best) best = o;
        }
        int dst = (best == ~0ULL) ? i : (int)((best - 1ULL) & 0x1fffULL);
        if (lane == k) mydst = dst;
        prev = best;   // uniform across lanes; sentinel sticks (pads forever)
    }

    // ---- pass 3: lanes 0..31 emit one edge each (f32 stores) ----
    if (lane < KNB) {
        const int e = i * KNB + lane;
        const int j = mydst;
        // edge_vec uses RAW (unwrapped) positions, per the reference.
        float ex = xi - pos[3*j + 0];
        float ey = yi - pos[3*j + 1];
        float ez = zi - pos[3*j + 2];
        float v2 = ex * ex;
        v2 = v2 + ey * ey;
        v2 = v2 + ez * ez;
        float w = (j != i) ? sqrtf(v2) : 0.0f;

        out[e]                = (float)i;   // src
        out[NK + e]           = (float)j;   // dst
        out[2 * NK + e]       = w;          // weight
        out[3 * NK + 3*e + 0] = ex;         // vec.x
        out[3 * NK + 3*e + 1] = ey;         // vec.y
        out[3 * NK + 3*e + 2] = ez;         // vec.z
    }
}

extern "C" void kernel_launch(void* const* d_in, const int* in_sizes, int n_in,
                              void* d_out, int out_size, void* d_ws, size_t ws_size,
                              hipStream_t stream) {
    const float* pos = (const float*)d_in[0];
    // d_in[1] = batch (all zeros, single system) -> ignored
    float* out = (float*)d_out;
    radius_graph_1pass<<<NATOMS / 4, 256, 0, stream>>>(pos, out);
}

// Round 18
// 121.081 us; speedup vs baseline: 15.7751x; 1.1818x over previous
//
#include <hip/hip_runtime.h>
#include <stdint.h>

// Periodic radius-graph (min-image), K nearest within cutoff, self-loop padded.
// N=8192, box 50^3, cutoff 6, K=32.
// Output (f32): [src (N*K) | dst (N*K) | weight (N*K) | vec (N*K,3)]
//
// PROVEN (r12/r17, absmax 0.0): d2 expression "E" = RN(RN(dx*dx+dz*dz)+dy*dy),
// key=((f32bits(d2)<<13)|j)+1, prev-successor selection, branch min-image wrap,
// raw-position edge vectors, f32 stores, LDS candidate compaction (CAP=128).
//
// THIS ROUND: 8x8x8 cell list (width 6.25 > cutoff 6). Scan only the 27
// neighbor cells (~432 candidates) instead of all 8192. Coverage proof:
// c(x)=clamp((int)(x*0.16f)) is monotone with threshold gaps ~6.25 > 6, so
// in-cutoff pairs are mod-8-adjacent in every dim regardless of rounding;
// box-wrap pairs land in cells {7,0}, adjacent mod 8. Candidate order changes
// but keys are totally ordered -> selection output invariant.

constexpr int NATOMS  = 8192;
constexpr int KNB     = 32;
constexpr int CAP     = 128;
constexpr int NK      = NATOMS * KNB;  // 262144 edges
constexpr int CELLCAP = 96;            // Poisson(16): P(>96) ~ 0
constexpr size_t WS_NEEDED = (512 + 512 * (size_t)CELLCAP) * sizeof(int);

__device__ __forceinline__ int cell_of(float x) {
    int c = (int)(x * 0.16f);          // 8/50; monotone, gaps ~6.25 > 6
    return c > 7 ? 7 : (c < 0 ? 0 : c);
}

__global__ __launch_bounds__(256) void build_cells(
    const float* __restrict__ pos, int* __restrict__ cnt, int* __restrict__ list)
{
    int i = blockIdx.x * 256 + threadIdx.x;
    if (i >= NATOMS) return;
    int cx = cell_of(pos[3*i + 0]);
    int cy = cell_of(pos[3*i + 1]);
    int cz = cell_of(pos[3*i + 2]);
    int c  = (cz * 8 + cy) * 8 + cx;
    int slot = atomicAdd(&cnt[c], 1);
    if (slot < CELLCAP) list[c * CELLCAP + slot] = i;
}

__global__ __launch_bounds__(256) void radius_graph_cells(
    const float* __restrict__ pos,
    const int* __restrict__ cnt, const int* __restrict__ list,
    float* __restrict__ out)
{
#pragma clang fp contract(off)
    __shared__ unsigned long long s_key[4][CAP];
    __shared__ int s_cnt[4];

    const int wv   = threadIdx.x >> 6;
    const int lane = threadIdx.x & 63;
    const int i    = (blockIdx.x << 2) + wv;   // atom handled by this wave

    const float xi = pos[3*i + 0];
    const float yi = pos[3*i + 1];
    const float zi = pos[3*i + 2];

    if (lane == 0) s_cnt[wv] = 0;
    __syncthreads();

    const int cx = cell_of(xi), cy = cell_of(yi), cz = cell_of(zi);

    // ---- pass 1: scan 27 neighbor cells, compact candidates (d2<=36) ----
    for (int oz = -1; oz <= 1; ++oz)
    for (int oy = -1; oy <= 1; ++oy)
    for (int ox = -1; ox <= 1; ++ox) {
        const int c = (((cz + oz) & 7) * 8 + ((cy + oy) & 7)) * 8 + ((cx + ox) & 7);
        int n = cnt[c];
        n = n > CELLCAP ? CELLCAP : n;
        const int* cl = list + c * CELLCAP;
        for (int t = lane; t < n; t += 64) {
            const int j = cl[t];
            float dx = xi - pos[3*j + 0];
            float dy = yi - pos[3*j + 1];
            float dz = zi - pos[3*j + 2];
            // min-image wrap (proven bitwise vs reference, r12/r17)
            dx = (dx >  25.0f) ? dx - 50.0f : dx;
            dx = (dx < -25.0f) ? dx + 50.0f : dx;
            dy = (dy >  25.0f) ? dy - 50.0f : dy;
            dy = (dy < -25.0f) ? dy + 50.0f : dy;
            dz = (dz >  25.0f) ? dz - 50.0f : dz;
            dz = (dz < -25.0f) ? dz + 50.0f : dz;
            // expression E (proven): rounded squares, (x+z) then +y
            float sx = dx * dx;
            float sy = dy * dy;
            float sz = dz * dz;
            float d2 = sx + sz;
            d2 = d2 + sy;
            if (d2 <= 36.0f) {
                unsigned long long key =
                    ((((unsigned long long)__float_as_uint(d2)) << 13)
                     | (unsigned long long)(unsigned)j) + 1ULL;
                int slot = atomicAdd(&s_cnt[wv], 1);
                if (slot < CAP) s_key[wv][slot] = key;
            }
        }
    }
    __syncthreads();

    int M = s_cnt[wv];
    if (M > CAP) M = CAP;

    // ---- pass 2: prev-successor selection over compacted keys (proven) ----
    unsigned long long k0 = ~0ULL, k1 = ~0ULL;
    if (lane < M)      k0 = s_key[wv][lane];
    if (lane + 64 < M) k1 = s_key[wv][lane + 64];

    unsigned long long prev = 0ULL;
    int mydst = i;
    for (int k = 0; k < KNB; ++k) {
        unsigned long long best = ~0ULL;
        if (k0 > prev && k0 < best) best = k0;
        if (k1 > prev && k1 < best) best = k1;
        #pragma unroll
        for (int off = 32; off > 0; off >>= 1) {
            unsigned long long o = __shfl_xor(best, off, 64);
            if (o < best) best = o;
        }
        int dst = (best == ~0ULL) ? i : (int)((best - 1ULL) & 0x1fffULL);
        if (lane == k) mydst = dst;
        prev = best;
    }

    // ---- pass 3: lanes 0..31 emit one edge each (proven) ----
    if (lane < KNB) {
        const int e = i * KNB + lane;
        const int j = mydst;
        float ex = xi - pos[3*j + 0];
        float ey = yi - pos[3*j + 1];
        float ez = zi - pos[3*j + 2];
        float v2 = ex * ex;
        v2 = v2 + ey * ey;
        v2 = v2 + ez * ez;
        float w = (j != i) ? sqrtf(v2) : 0.0f;

        out[e]                = (float)i;
        out[NK + e]           = (float)j;
        out[2 * NK + e]       = w;
        out[3 * NK + 3*e + 0] = ex;
        out[3 * NK + 3*e + 1] = ey;
        out[3 * NK + 3*e + 2] = ez;
    }
}

// ---- proven fallback (r17): full scan, used only if ws too small ----
__global__ __launch_bounds__(256) void radius_graph_1pass(
    const float* __restrict__ pos, float* __restrict__ out)
{
#pragma clang fp contract(off)
    __shared__ unsigned long long s_key[4][CAP];
    __shared__ int s_cnt[4];
    const int wv = threadIdx.x >> 6, lane = threadIdx.x & 63;
    const int i  = (blockIdx.x << 2) + wv;
    const float xi = pos[3*i+0], yi = pos[3*i+1], zi = pos[3*i+2];
    if (lane == 0) s_cnt[wv] = 0;
    __syncthreads();
    for (int j = lane; j < NATOMS; j += 64) {
        float dx = xi - pos[3*j+0], dy = yi - pos[3*j+1], dz = zi - pos[3*j+2];
        dx = (dx >  25.0f) ? dx - 50.0f : dx;
        dx = (dx < -25.0f) ? dx + 50.0f : dx;
        dy = (dy >  25.0f) ? dy - 50.0f : dy;
        dy = (dy < -25.0f) ? dy + 50.0f : dy;
        dz = (dz >  25.0f) ? dz - 50.0f : dz;
        dz = (dz < -25.0f) ? dz + 50.0f : dz;
        float sx = dx*dx, sy = dy*dy, sz = dz*dz;
        float d2 = sx + sz; d2 = d2 + sy;
        if (d2 <= 36.0f) {
            unsigned long long key =
                ((((unsigned long long)__float_as_uint(d2)) << 13)
                 | (unsigned long long)(unsigned)j) + 1ULL;
            int slot = atomicAdd(&s_cnt[wv], 1);
            if (slot < CAP) s_key[wv][slot] = key;
        }
    }
    __syncthreads();
    int M = s_cnt[wv]; if (M > CAP) M = CAP;
    unsigned long long k0 = ~0ULL, k1 = ~0ULL;
    if (lane < M)      k0 = s_key[wv][lane];
    if (lane + 64 < M) k1 = s_key[wv][lane + 64];
    unsigned long long prev = 0ULL;
    int mydst = i;
    for (int k = 0; k < KNB; ++k) {
        unsigned long long best = ~0ULL;
        if (k0 > prev && k0 < best) best = k0;
        if (k1 > prev && k1 < best) best = k1;
        #pragma unroll
        for (int off = 32; off > 0; off >>= 1) {
            unsigned long long o = __shfl_xor(best, off, 64);
            if (o < best) best = o;
        }
        int dst = (best == ~0ULL) ? i : (int)((best - 1ULL) & 0x1fffULL);
        if (lane == k) mydst = dst;
        prev = best;
    }
    if (lane < KNB) {
        const int e = i * KNB + lane;
        const int j = mydst;
        float ex = xi - pos[3*j+0], ey = yi - pos[3*j+1], ez = zi - pos[3*j+2];
        float v2 = ex*ex; v2 = v2 + ey*ey; v2 = v2 + ez*ez;
        float w = (j != i) ? sqrtf(v2) : 0.0f;
        out[e] = (float)i;  out[NK + e] = (float)j;  out[2*NK + e] = w;
        out[3*NK + 3*e+0] = ex; out[3*NK + 3*e+1] = ey; out[3*NK + 3*e+2] = ez;
    }
}

extern "C" void kernel_launch(void* const* d_in, const int* in_sizes, int n_in,
                              void* d_out, int out_size, void* d_ws, size_t ws_size,
                              hipStream_t stream) {
    const float* pos = (const float*)d_in[0];
    float* out = (float*)d_out;
    if (ws_size >= WS_NEEDED) {
        int* cnt  = (int*)d_ws;
        int* list = cnt + 512;
        hipMemsetAsync(cnt, 0, 512 * sizeof(int), stream);
        build_cells<<<NATOMS / 256, 256, 0, stream>>>(pos, cnt, list);
        radius_graph_cells<<<NATOMS / 4, 256, 0, stream>>>(pos, cnt, list, out);
    } else {
        radius_graph_1pass<<<NATOMS / 4, 256, 0, stream>>>(pos, out);
    }
}